// Round 1
// baseline (419.726 us; speedup 1.0000x reference)
//
#include <hip/hip_runtime.h>
#include <hip/hip_bf16.h>
#include <stdint.h>

#define M_DIM 8192   // rows of x / out
#define K_DIM 4096   // inner dim
#define N_DIM 4096   // cols of out = rows of W

typedef int intx4 __attribute__((ext_vector_type(4)));

// ---------------------------------------------------------------------------
// Fused conversion:
//   blocks [0, 8192):      one block per row of x -> per-row absmax-quant i8
//   blocks [8192, 16384):  w fp32 -> sign as i8, 8 elems/thread
// ---------------------------------------------------------------------------
__global__ void cvt_fused_i8_kernel(const float* __restrict__ x,
                                    const float* __restrict__ w,
                                    signed char* __restrict__ xb,
                                    signed char* __restrict__ wb,
                                    float* __restrict__ row_scale) {
    const int b   = blockIdx.x;
    const int tid = threadIdx.x;
    if (b < M_DIM) {
        // quantize one 4096-element row of x; fully coalesced loads:
        // thread t holds elems {t*4 + i*1024}, wave covers 1 KiB/instr
        __shared__ float wmax[4];
        const float* xr = x + (size_t)b * K_DIM;
        float4 v[4];
#pragma unroll
        for (int i = 0; i < 4; ++i)
            v[i] = *(const float4*)(xr + tid * 4 + i * 1024);

        float am = 0.f;
#pragma unroll
        for (int i = 0; i < 4; ++i) {
            am = fmaxf(am, fabsf(v[i].x)); am = fmaxf(am, fabsf(v[i].y));
            am = fmaxf(am, fabsf(v[i].z)); am = fmaxf(am, fabsf(v[i].w));
        }
        // wave reduce (64 lanes)
#pragma unroll
        for (int off = 32; off > 0; off >>= 1)
            am = fmaxf(am, __shfl_xor(am, off));
        if ((tid & 63) == 0) wmax[tid >> 6] = am;
        __syncthreads();
        am = fmaxf(fmaxf(wmax[0], wmax[1]), fmaxf(wmax[2], wmax[3]));
        am = fmaxf(am, 1e-30f);

        const float inv = 127.f / am;
#pragma unroll
        for (int i = 0; i < 4; ++i) {
            union { signed char c[4]; uint32_t u; } r;
            const float* vf = (const float*)&v[i];
#pragma unroll
            for (int k = 0; k < 4; ++k) {
                int q = (int)rintf(vf[k] * inv);
                q = q > 127 ? 127 : (q < -127 ? -127 : q);
                r.c[k] = (signed char)q;
            }
            *(uint32_t*)(xb + (size_t)b * K_DIM + tid * 4 + i * 1024) = r.u;
        }
        if (tid == 0) row_scale[b] = am * (1.f / 127.f);
    } else {
        // sign(w) -> i8, 8 elems/thread
        size_t t = ((size_t)(b - M_DIM) * blockDim.x + tid) * 8;
        float4 a = *(const float4*)(w + t);
        float4 c = *(const float4*)(w + t + 4);
        union { signed char s[8]; uint2 u; } r;
        r.s[0] = (a.x > 0.f) - (a.x < 0.f); r.s[1] = (a.y > 0.f) - (a.y < 0.f);
        r.s[2] = (a.z > 0.f) - (a.z < 0.f); r.s[3] = (a.w > 0.f) - (a.w < 0.f);
        r.s[4] = (c.x > 0.f) - (c.x < 0.f); r.s[5] = (c.y > 0.f) - (c.y < 0.f);
        r.s[6] = (c.z > 0.f) - (c.z < 0.f); r.s[7] = (c.w > 0.f) - (c.w < 0.f);
        *(uint2*)(wb + t) = r.u;
    }
}

__device__ __forceinline__ void gld_lds16(const void* g, void* l) {
    __builtin_amdgcn_global_load_lds(
        (const __attribute__((address_space(1))) void*)g,
        (__attribute__((address_space(3))) void*)l,
        16, 0, 0);
}

// ---------------------------------------------------------------------------
// i8 GEMM, 8-phase-template port (T1+T2+T3/T4+T5):
//   256x256 block tile, BK=64 (i8), 512 threads = 8 waves (2M x 4N),
//   per-wave C = 128x64 via 16x16x64 MFMA.
//   LDS: 4-slot ring of K-tiles (4 x (16K A + 16K B) = 128 KiB) ->
//        prefetch distance 3, counted vmcnt(8) in steady state (never 0).
//   LDS XOR-swizzle chunk^((row>>1)&3): linear gld_lds dest + pre-swizzled
//   per-lane GLOBAL source + swizzled ds_read (both-sides rule).
//   2 phases per K-tile (M-half each): {ds_read || stage-issue; barrier;
//   lgkmcnt(0); setprio(1); 16 MFMA; setprio(0); barrier}.
// ---------------------------------------------------------------------------
__global__ void __launch_bounds__(512, 2)
gemm_i8_kernel(const signed char* __restrict__ A,
               const signed char* __restrict__ B,
               const float* __restrict__ bias,
               const float* __restrict__ scale,
               const float* __restrict__ row_scale,
               float* __restrict__ out) {
    __shared__ __attribute__((aligned(16))) signed char sA[4][256 * 64];
    __shared__ __attribute__((aligned(16))) signed char sB[4][256 * 64];

    const int tid  = threadIdx.x;
    const int lane = tid & 63;
    const int wave = tid >> 6;   // 0..7
    const int wm = wave >> 2;    // wave row 0..1  (128 rows each)
    const int wn = wave & 3;     // wave col 0..3  (64 cols each)
    const int g  = lane >> 4;    // quad 0..3
    const int mn = lane & 15;

    // XCD-bijective swizzle: 512 blocks = 8 XCDs x 64; n-fast within XCD
    const int bid = blockIdx.x;
    const int swz = (bid & 7) * 64 + (bid >> 3);
    const int n_idx = swz & 15;
    const int m_idx = swz >> 4;
    const int rowBase = m_idx * 256;
    const int colBase = n_idx * 256;

    // ---- staging addressing (per wave: 16 rows per gld round) ----
    // LDS dest is linear (gld_lds writes base + lane*16); source chunk is
    // pre-swizzled: chunk' = (lane&3) ^ f(row), f(row) = ((row mod 16)>>1)&3
    // which reduces to (lane>>3)&3 for the staging lane->row map.
    const int sc   = (lane & 3) ^ ((lane >> 3) & 3);
    const int srow = wave * 16 + (lane >> 2);           // 0..127
    const signed char* gA0 = A + (size_t)(rowBase + srow) * K_DIM + sc * 16;
    const signed char* gA1 = gA0 + (size_t)128 * K_DIM;
    const signed char* gB0 = B + (size_t)(colBase + srow) * K_DIM + sc * 16;
    const signed char* gB1 = gB0 + (size_t)128 * K_DIM;
    const int ldsR0 = wave * 1024;          // rows wave*16..        (x64 B)
    const int ldsR1 = 8192 + wave * 1024;   // rows 128+wave*16..

    // ---- fragment read offsets (same XOR on the read side) ----
    const int fxor = (g ^ ((mn >> 1) & 3)) * 16;
    const int aoff = (wm * 128 + mn) * 64 + fxor;
    const int boff = (wn * 64 + mn) * 64 + fxor;

    intx4 acc0[4][4] = {};   // M-half 0
    intx4 acc1[4][4] = {};   // M-half 1

    // ---- prologue: stage K-tiles 0,1,2 (12 glds/wave) ----
#pragma unroll
    for (int s = 0; s < 3; ++s) {
        const size_t kg = (size_t)s * 64;
        gld_lds16(gA0 + kg, &sA[s][ldsR0]);
        gld_lds16(gA1 + kg, &sA[s][ldsR1]);
        gld_lds16(gB0 + kg, &sB[s][ldsR0]);
        gld_lds16(gB1 + kg, &sB[s][ldsR1]);
    }
    asm volatile("s_waitcnt vmcnt(8)" ::: "memory");  // tile 0 landed
    __builtin_amdgcn_s_barrier();

    for (int t = 0; t < 64; ++t) {
        const signed char* sAb = sA[t & 3];
        const signed char* sBb = sB[t & 3];
        signed char* pA = sA[(t + 3) & 3];   // slot last read at tile t-1: safe
        signed char* pB = sB[(t + 3) & 3];
        const bool stage = t < 61;
        const size_t kg = (size_t)(t + 3) * 64;

        // ============== phase 0: M-half 0 ==============
        intx4 a0[4], b0[4];
#pragma unroll
        for (int i = 0; i < 4; ++i)
            a0[i] = *(const intx4*)(sAb + aoff + i * 1024);
#pragma unroll
        for (int j = 0; j < 4; ++j)
            b0[j] = *(const intx4*)(sBb + boff + j * 1024);
        if (stage) {
            gld_lds16(gA0 + kg, pA + ldsR0);
            gld_lds16(gA1 + kg, pA + ldsR1);
        }
        __builtin_amdgcn_s_barrier();
        asm volatile("s_waitcnt lgkmcnt(0)" ::: "memory");
        __builtin_amdgcn_sched_barrier(0);
        __builtin_amdgcn_s_setprio(1);
#pragma unroll
        for (int i = 0; i < 4; ++i)
#pragma unroll
            for (int j = 0; j < 4; ++j)
                acc0[i][j] = __builtin_amdgcn_mfma_i32_16x16x64_i8(
                    a0[i], b0[j], acc0[i][j], 0, 0, 0);
        __builtin_amdgcn_s_setprio(0);
        __builtin_amdgcn_sched_barrier(0);
        __builtin_amdgcn_s_barrier();

        // ============== phase 1: M-half 1 ==============
        intx4 a1[4];
#pragma unroll
        for (int i = 0; i < 4; ++i)
            a1[i] = *(const intx4*)(sAb + aoff + 4096 + i * 1024);
        if (stage) {
            gld_lds16(gB0 + kg, pB + ldsR0);
            gld_lds16(gB1 + kg, pB + ldsR1);
        }
        __builtin_amdgcn_s_barrier();
        asm volatile("s_waitcnt lgkmcnt(0)" ::: "memory");
        __builtin_amdgcn_sched_barrier(0);
        __builtin_amdgcn_s_setprio(1);
#pragma unroll
        for (int i = 0; i < 4; ++i)
#pragma unroll
            for (int j = 0; j < 4; ++j)
                acc1[i][j] = __builtin_amdgcn_mfma_i32_16x16x64_i8(
                    a1[i], b0[j], acc1[i][j], 0, 0, 0);
        __builtin_amdgcn_s_setprio(0);
        __builtin_amdgcn_sched_barrier(0);

        // ---- K-tile boundary: counted drain so tile t+1 is resident ----
        // steady state: 8 younger glds in flight (tiles t+2, t+3)
        if (t < 61)       asm volatile("s_waitcnt vmcnt(8)" ::: "memory");
        else if (t == 61) asm volatile("s_waitcnt vmcnt(4)" ::: "memory");
        else if (t == 62) asm volatile("s_waitcnt vmcnt(0)" ::: "memory");
        __builtin_amdgcn_s_barrier();
    }

    // ---- epilogue: C/D layout col = mn, row = g*4 + reg (dtype-indep) ----
    const float s = scale[0];
#pragma unroll
    for (int j = 0; j < 4; ++j) {
        const int gcol = colBase + wn * 64 + j * 16 + mn;
        const float bv = bias[gcol];
#pragma unroll
        for (int i = 0; i < 4; ++i) {
            {
                const int grow0 = rowBase + wm * 128 + i * 16 + g * 4;
                const float4 rs4 = *(const float4*)(row_scale + grow0);
                const float rs[4] = {rs4.x, rs4.y, rs4.z, rs4.w};
#pragma unroll
                for (int r = 0; r < 4; ++r)
                    __builtin_nontemporal_store(
                        s * ((float)acc0[i][j][r] * rs[r] + bv),
                        out + (size_t)(grow0 + r) * N_DIM + gcol);
            }
            {
                const int grow1 = rowBase + wm * 128 + 64 + i * 16 + g * 4;
                const float4 rs4 = *(const float4*)(row_scale + grow1);
                const float rs[4] = {rs4.x, rs4.y, rs4.z, rs4.w};
#pragma unroll
                for (int r = 0; r < 4; ++r)
                    __builtin_nontemporal_store(
                        s * ((float)acc1[i][j][r] * rs[r] + bv),
                        out + (size_t)(grow1 + r) * N_DIM + gcol);
            }
        }
    }
}

// slow but correct fp32 fallback (only if workspace is too small)
__global__ void fallback_kernel(const float* __restrict__ x,
                                const float* __restrict__ w,
                                const float* __restrict__ bias,
                                const float* __restrict__ scale,
                                float* __restrict__ out) {
    int col = blockIdx.x * 64 + (threadIdx.x & 63);
    int row = blockIdx.y * 4 + (threadIdx.x >> 6);
    const float* xr = x + (size_t)row * K_DIM;
    const float* wr = w + (size_t)col * K_DIM;
    float acc = 0.f;
    for (int k = 0; k < K_DIM; k += 4) {
        float4 a = *(const float4*)(xr + k);
        float4 b = *(const float4*)(wr + k);
        acc += a.x * (b.x > 0.f ? 1.f : (b.x < 0.f ? -1.f : 0.f));
        acc += a.y * (b.y > 0.f ? 1.f : (b.y < 0.f ? -1.f : 0.f));
        acc += a.z * (b.z > 0.f ? 1.f : (b.z < 0.f ? -1.f : 0.f));
        acc += a.w * (b.w > 0.f ? 1.f : (b.w < 0.f ? -1.f : 0.f));
    }
    out[(size_t)row * N_DIM + col] = scale[0] * (acc + bias[col]);
}

extern "C" void kernel_launch(void* const* d_in, const int* in_sizes, int n_in,
                              void* d_out, int out_size, void* d_ws, size_t ws_size,
                              hipStream_t stream) {
    const float* x     = (const float*)d_in[0];
    const float* w     = (const float*)d_in[1];
    const float* bias  = (const float*)d_in[2];
    const float* scale = (const float*)d_in[3];
    float* out = (float*)d_out;

    const size_t xb_bytes = (size_t)M_DIM * K_DIM;          // 32 MiB
    const size_t wb_bytes = (size_t)N_DIM * K_DIM;          // 16 MiB
    const size_t need = xb_bytes + wb_bytes + M_DIM * sizeof(float);

    if (ws_size >= need) {
        signed char* xb = (signed char*)d_ws;
        signed char* wb = xb + xb_bytes;
        float* row_scale = (float*)(wb + wb_bytes);
        const unsigned w_blocks = (unsigned)((size_t)N_DIM * K_DIM / 8 / 256); // 8192
        cvt_fused_i8_kernel<<<dim3(M_DIM + w_blocks), 256, 0, stream>>>(
            x, w, xb, wb, row_scale);
        gemm_i8_kernel<<<dim3((M_DIM / 256) * (N_DIM / 256)), 512, 0, stream>>>(
            xb, wb, bias, scale, row_scale, out);
    } else {
        dim3 grid(N_DIM / 64, M_DIM / 4);
        fallback_kernel<<<grid, 256, 0, stream>>>(x, w, bias, scale, out);
    }
}

// Round 2
// 405.110 us; speedup vs baseline: 1.0361x; 1.0361x over previous
//
#include <hip/hip_runtime.h>
#include <hip/hip_bf16.h>
#include <stdint.h>

#define M_DIM 8192   // rows of x / out
#define K_DIM 4096   // inner dim
#define N_DIM 4096   // cols of out = rows of W

typedef int intx4  __attribute__((ext_vector_type(4)));
typedef int intx16 __attribute__((ext_vector_type(16)));

// ---------------------------------------------------------------------------
// Fused conversion:
//   blocks [0, 8192):      one block per row of x -> per-row absmax-quant i8
//   blocks [8192, 16384):  w fp32 -> sign as i8, 8 elems/thread
// ---------------------------------------------------------------------------
__global__ void cvt_fused_i8_kernel(const float* __restrict__ x,
                                    const float* __restrict__ w,
                                    signed char* __restrict__ xb,
                                    signed char* __restrict__ wb,
                                    float* __restrict__ row_scale) {
    const int b   = blockIdx.x;
    const int tid = threadIdx.x;
    if (b < M_DIM) {
        // quantize one 4096-element row of x; fully coalesced loads
        __shared__ float wmax[4];
        const float* xr = x + (size_t)b * K_DIM;
        float4 v[4];
#pragma unroll
        for (int i = 0; i < 4; ++i)
            v[i] = *(const float4*)(xr + tid * 4 + i * 1024);

        float am = 0.f;
#pragma unroll
        for (int i = 0; i < 4; ++i) {
            am = fmaxf(am, fabsf(v[i].x)); am = fmaxf(am, fabsf(v[i].y));
            am = fmaxf(am, fabsf(v[i].z)); am = fmaxf(am, fabsf(v[i].w));
        }
#pragma unroll
        for (int off = 32; off > 0; off >>= 1)
            am = fmaxf(am, __shfl_xor(am, off));
        if ((tid & 63) == 0) wmax[tid >> 6] = am;
        __syncthreads();
        am = fmaxf(fmaxf(wmax[0], wmax[1]), fmaxf(wmax[2], wmax[3]));
        am = fmaxf(am, 1e-30f);

        const float inv = 127.f / am;
#pragma unroll
        for (int i = 0; i < 4; ++i) {
            union { signed char c[4]; uint32_t u; } r;
            const float* vf = (const float*)&v[i];
#pragma unroll
            for (int k = 0; k < 4; ++k) {
                int q = (int)rintf(vf[k] * inv);
                q = q > 127 ? 127 : (q < -127 ? -127 : q);
                r.c[k] = (signed char)q;
            }
            *(uint32_t*)(xb + (size_t)b * K_DIM + tid * 4 + i * 1024) = r.u;
        }
        if (tid == 0) row_scale[b] = am * (1.f / 127.f);
    } else {
        // sign(w) -> i8, 8 elems/thread
        size_t t = ((size_t)(b - M_DIM) * blockDim.x + tid) * 8;
        float4 a = *(const float4*)(w + t);
        float4 c = *(const float4*)(w + t + 4);
        union { signed char s[8]; uint2 u; } r;
        r.s[0] = (a.x > 0.f) - (a.x < 0.f); r.s[1] = (a.y > 0.f) - (a.y < 0.f);
        r.s[2] = (a.z > 0.f) - (a.z < 0.f); r.s[3] = (a.w > 0.f) - (a.w < 0.f);
        r.s[4] = (c.x > 0.f) - (c.x < 0.f); r.s[5] = (c.y > 0.f) - (c.y < 0.f);
        r.s[6] = (c.z > 0.f) - (c.z < 0.f); r.s[7] = (c.w > 0.f) - (c.w < 0.f);
        *(uint2*)(wb + t) = r.u;
    }
}

__device__ __forceinline__ void gld_lds16(const void* g, void* l) {
    __builtin_amdgcn_global_load_lds(
        (const __attribute__((address_space(1))) void*)g,
        (__attribute__((address_space(3))) void*)l,
        16, 0, 0);
}

// ---------------------------------------------------------------------------
// i8 GEMM: 256x256 tile, BK=64, 512 thr = 8 waves (2M x 4N), wave C = 128x64
// via mfma_i32_32x32x32_i8 (acc[4][2] x intx16).
//
// Pipeline (the round-1 fix: fragment-level ping-pong, ONE barrier/K-tile):
//   per tile t (slot t&3): fragsE (k-step0) pre-read during tile t-1.
//     issue fragsO reads (k-step1) + 4 gld_lds (tile t+3)
//     MFMA x8 (E)            <- compiler auto lgkmcnt(6): O reads in flight
//     issue fragsE' reads (tile t+1 k-step0, slot t+1 resident by protocol)
//     MFMA x8 (O)            <- auto lgkmcnt(6): E' reads in flight
//     vmcnt(4)  [tiles t+1 AND t+2 resident]  ;  s_barrier
//   -> every ds_read retires under an MFMA shadow; lgkmcnt never drains to 0.
//
// LDS ring: 4 slots (4 x 16K A + 4 x 16K B = 128 KiB), prefetch distance 3.
// Hazards: writes at tile t -> slot (t-1)&3, whose reads completed before the
// tile-t entry barrier; E' reads -> slot (t+1)&3, disjoint from write slot.
//
// XOR-swizzle chunk^((row>>1)&3) both-sides (pre-swizzled global src +
// swizzled ds_read): conflict-free for the 32x32 fragment map
// (row = lane&31, chunk = (lane>>5) + 2*kstep).
// ---------------------------------------------------------------------------
__global__ void __launch_bounds__(512, 2)
gemm_i8_kernel(const signed char* __restrict__ A,
               const signed char* __restrict__ B,
               const float* __restrict__ bias,
               const float* __restrict__ scale,
               const float* __restrict__ row_scale,
               float* __restrict__ out) {
    __shared__ __attribute__((aligned(16))) signed char sA[4][256 * 64];
    __shared__ __attribute__((aligned(16))) signed char sB[4][256 * 64];

    const int tid  = threadIdx.x;
    const int lane = tid & 63;
    const int wave = tid >> 6;   // 0..7
    const int wm = wave >> 2;    // 0..1 : 128-row half
    const int wn = wave & 3;     // 0..3 : 64-col slice
    const int r5 = lane & 31;
    const int hi = lane >> 5;

    // XCD-bijective swizzle: 512 blocks = 8 XCDs x 64; n-fast within XCD
    const int bid = blockIdx.x;
    const int swz = (bid & 7) * 64 + (bid >> 3);
    const int rowBase = (swz >> 4) * 256;
    const int colBase = (swz & 15) * 256;

    // ---- staging addressing (per wave: 16 rows per gld; linear LDS dest,
    //      pre-swizzled global chunk; matches read-side f(row)=(row>>1)&3) ----
    const int sc   = (lane & 3) ^ ((lane >> 3) & 3);
    const int srow = wave * 16 + (lane >> 2);
    const signed char* gA0 = A + (size_t)(rowBase + srow) * K_DIM + sc * 16;
    const signed char* gA1 = gA0 + (size_t)128 * K_DIM;
    const signed char* gB0 = B + (size_t)(colBase + srow) * K_DIM + sc * 16;
    const signed char* gB1 = gB0 + (size_t)128 * K_DIM;
    const int ldsR0 = wave * 1024;
    const int ldsR1 = 8192 + wave * 1024;

    // ---- fragment read offsets (32x32x32: row=lane&31, chunk=hi+2*kstep) ----
    const int fsw = (r5 >> 1) & 3;
    const int ckE = ((hi + 0) ^ fsw) * 16;    // k-step 0: logical chunks {0,1}
    const int ckO = ((hi + 2) ^ fsw) * 16;    // k-step 1: logical chunks {2,3}
    const int aOff = (wm * 128 + r5) * 64;    // + mt*2048
    const int bOff = (wn * 64 + r5) * 64;     // + nt*2048

    intx16 acc[4][2] = {};
    intx4 fa[4], fb[2];   // even k-step frags (current tile)
    intx4 oa[4], ob[2];   // odd  k-step frags

    // ---- prologue: stage tiles 0,1,2 (12 glds/wave) ----
#pragma unroll
    for (int s = 0; s < 3; ++s) {
        const size_t kg = (size_t)s * 64;
        gld_lds16(gA0 + kg, &sA[s][ldsR0]);
        gld_lds16(gA1 + kg, &sA[s][ldsR1]);
        gld_lds16(gB0 + kg, &sB[s][ldsR0]);
        gld_lds16(gB1 + kg, &sB[s][ldsR1]);
    }
    asm volatile("s_waitcnt vmcnt(4)" ::: "memory");  // tiles 0,1 resident
    __builtin_amdgcn_s_barrier();

    // pre-read even frags of tile 0
#pragma unroll
    for (int mt = 0; mt < 4; ++mt)
        fa[mt] = *(const intx4*)(&sA[0][0] + aOff + mt * 2048 + ckE);
#pragma unroll
    for (int nt = 0; nt < 2; ++nt)
        fb[nt] = *(const intx4*)(&sB[0][0] + bOff + nt * 2048 + ckE);

    for (int t = 0; t < 64; ++t) {
        const signed char* sAb = sA[t & 3];
        const signed char* sBb = sB[t & 3];
        const signed char* sAn = sA[(t + 1) & 3];
        const signed char* sBn = sB[(t + 1) & 3];

        // ---- issue odd-k-step reads + stage tile t+3 ----
#pragma unroll
        for (int mt = 0; mt < 4; ++mt)
            oa[mt] = *(const intx4*)(sAb + aOff + mt * 2048 + ckO);
#pragma unroll
        for (int nt = 0; nt < 2; ++nt)
            ob[nt] = *(const intx4*)(sBb + bOff + nt * 2048 + ckO);
        if (t < 61) {
            signed char* pA = sA[(t + 3) & 3];
            signed char* pB = sB[(t + 3) & 3];
            const size_t kg = (size_t)(t + 3) * 64;
            gld_lds16(gA0 + kg, pA + ldsR0);
            gld_lds16(gA1 + kg, pA + ldsR1);
            gld_lds16(gB0 + kg, pB + ldsR0);
            gld_lds16(gB1 + kg, pB + ldsR1);
        }
        __builtin_amdgcn_sched_barrier(0);

        // ---- MFMA even k-step (odd reads + glds fly underneath) ----
        __builtin_amdgcn_s_setprio(1);
#pragma unroll
        for (int mt = 0; mt < 4; ++mt)
#pragma unroll
            for (int nt = 0; nt < 2; ++nt)
                acc[mt][nt] = __builtin_amdgcn_mfma_i32_32x32x32_i8(
                    fa[mt], fb[nt], acc[mt][nt], 0, 0, 0);
        __builtin_amdgcn_s_setprio(0);
        __builtin_amdgcn_sched_barrier(0);

        // ---- issue next-tile even-k-step reads (slot t+1 is resident) ----
#pragma unroll
        for (int mt = 0; mt < 4; ++mt)
            fa[mt] = *(const intx4*)(sAn + aOff + mt * 2048 + ckE);
#pragma unroll
        for (int nt = 0; nt < 2; ++nt)
            fb[nt] = *(const intx4*)(sBn + bOff + nt * 2048 + ckE);
        __builtin_amdgcn_sched_barrier(0);

        // ---- MFMA odd k-step (next-tile reads fly underneath) ----
        __builtin_amdgcn_s_setprio(1);
#pragma unroll
        for (int mt = 0; mt < 4; ++mt)
#pragma unroll
            for (int nt = 0; nt < 2; ++nt)
                acc[mt][nt] = __builtin_amdgcn_mfma_i32_32x32x32_i8(
                    oa[mt], ob[nt], acc[mt][nt], 0, 0, 0);
        __builtin_amdgcn_s_setprio(0);
        __builtin_amdgcn_sched_barrier(0);

        // ---- K-tile boundary: counted drain, ONE barrier ----
        if (t < 61)       asm volatile("s_waitcnt vmcnt(4)" ::: "memory");
        else if (t == 61) asm volatile("s_waitcnt vmcnt(0)" ::: "memory");
        __builtin_amdgcn_s_barrier();
    }

    // ---- epilogue: 32x32 C/D layout col=lane&31, row=(reg&3)+8*(reg>>2)+4*hi
    const float s = scale[0];
#pragma unroll
    for (int nt = 0; nt < 2; ++nt) {
        const int gcol = colBase + wn * 64 + nt * 32 + r5;
        const float bv = bias[gcol];
#pragma unroll
        for (int mt = 0; mt < 4; ++mt) {
#pragma unroll
            for (int q = 0; q < 4; ++q) {
                const int row0 = rowBase + wm * 128 + mt * 32 + q * 8 + hi * 4;
                const float4 rs4 = *(const float4*)(row_scale + row0);
                const float rs[4] = {rs4.x, rs4.y, rs4.z, rs4.w};
#pragma unroll
                for (int r = 0; r < 4; ++r)
                    __builtin_nontemporal_store(
                        s * ((float)acc[mt][nt][q * 4 + r] * rs[r] + bv),
                        out + (size_t)(row0 + r) * N_DIM + gcol);
            }
        }
    }
}

// slow but correct fp32 fallback (only if workspace is too small)
__global__ void fallback_kernel(const float* __restrict__ x,
                                const float* __restrict__ w,
                                const float* __restrict__ bias,
                                const float* __restrict__ scale,
                                float* __restrict__ out) {
    int col = blockIdx.x * 64 + (threadIdx.x & 63);
    int row = blockIdx.y * 4 + (threadIdx.x >> 6);
    const float* xr = x + (size_t)row * K_DIM;
    const float* wr = w + (size_t)col * K_DIM;
    float acc = 0.f;
    for (int k = 0; k < K_DIM; k += 4) {
        float4 a = *(const float4*)(xr + k);
        float4 b = *(const float4*)(wr + k);
        acc += a.x * (b.x > 0.f ? 1.f : (b.x < 0.f ? -1.f : 0.f));
        acc += a.y * (b.y > 0.f ? 1.f : (b.y < 0.f ? -1.f : 0.f));
        acc += a.z * (b.z > 0.f ? 1.f : (b.z < 0.f ? -1.f : 0.f));
        acc += a.w * (b.w > 0.f ? 1.f : (b.w < 0.f ? -1.f : 0.f));
    }
    out[(size_t)row * N_DIM + col] = scale[0] * (acc + bias[col]);
}

extern "C" void kernel_launch(void* const* d_in, const int* in_sizes, int n_in,
                              void* d_out, int out_size, void* d_ws, size_t ws_size,
                              hipStream_t stream) {
    const float* x     = (const float*)d_in[0];
    const float* w     = (const float*)d_in[1];
    const float* bias  = (const float*)d_in[2];
    const float* scale = (const float*)d_in[3];
    float* out = (float*)d_out;

    const size_t xb_bytes = (size_t)M_DIM * K_DIM;          // 32 MiB
    const size_t wb_bytes = (size_t)N_DIM * K_DIM;          // 16 MiB
    const size_t need = xb_bytes + wb_bytes + M_DIM * sizeof(float);

    if (ws_size >= need) {
        signed char* xb = (signed char*)d_ws;
        signed char* wb = xb + xb_bytes;
        float* row_scale = (float*)(wb + wb_bytes);
        const unsigned w_blocks = (unsigned)((size_t)N_DIM * K_DIM / 8 / 256); // 8192
        cvt_fused_i8_kernel<<<dim3(M_DIM + w_blocks), 256, 0, stream>>>(
            x, w, xb, wb, row_scale);
        gemm_i8_kernel<<<dim3((M_DIM / 256) * (N_DIM / 256)), 512, 0, stream>>>(
            xb, wb, bias, scale, row_scale, out);
    } else {
        dim3 grid(N_DIM / 64, M_DIM / 4);
        fallback_kernel<<<grid, 256, 0, stream>>>(x, w, bias, scale, out);
    }
}

// Round 3
// 403.220 us; speedup vs baseline: 1.0409x; 1.0047x over previous
//
#include <hip/hip_runtime.h>
#include <hip/hip_bf16.h>
#include <stdint.h>

#define M_DIM 8192   // rows of x / out
#define K_DIM 4096   // inner dim
#define N_DIM 4096   // cols of out = rows of W

typedef int intx4  __attribute__((ext_vector_type(4)));
typedef int intx16 __attribute__((ext_vector_type(16)));

// ---------------------------------------------------------------------------
// Fused conversion:
//   blocks [0, 8192):      one block per row of x -> per-row absmax-quant i8
//   blocks [8192, 16384):  w fp32 -> sign as i8, 8 elems/thread
// ---------------------------------------------------------------------------
__global__ void cvt_fused_i8_kernel(const float* __restrict__ x,
                                    const float* __restrict__ w,
                                    signed char* __restrict__ xb,
                                    signed char* __restrict__ wb,
                                    float* __restrict__ row_scale) {
    const int b   = blockIdx.x;
    const int tid = threadIdx.x;
    if (b < M_DIM) {
        // quantize one 4096-element row of x; fully coalesced loads
        __shared__ float wmax[4];
        const float* xr = x + (size_t)b * K_DIM;
        float4 v[4];
#pragma unroll
        for (int i = 0; i < 4; ++i)
            v[i] = *(const float4*)(xr + tid * 4 + i * 1024);

        float am = 0.f;
#pragma unroll
        for (int i = 0; i < 4; ++i) {
            am = fmaxf(am, fabsf(v[i].x)); am = fmaxf(am, fabsf(v[i].y));
            am = fmaxf(am, fabsf(v[i].z)); am = fmaxf(am, fabsf(v[i].w));
        }
#pragma unroll
        for (int off = 32; off > 0; off >>= 1)
            am = fmaxf(am, __shfl_xor(am, off));
        if ((tid & 63) == 0) wmax[tid >> 6] = am;
        __syncthreads();
        am = fmaxf(fmaxf(wmax[0], wmax[1]), fmaxf(wmax[2], wmax[3]));
        am = fmaxf(am, 1e-30f);

        const float inv = 127.f / am;
#pragma unroll
        for (int i = 0; i < 4; ++i) {
            union { signed char c[4]; uint32_t u; } r;
            const float* vf = (const float*)&v[i];
#pragma unroll
            for (int k = 0; k < 4; ++k) {
                int q = (int)rintf(vf[k] * inv);
                q = q > 127 ? 127 : (q < -127 ? -127 : q);
                r.c[k] = (signed char)q;
            }
            *(uint32_t*)(xb + (size_t)b * K_DIM + tid * 4 + i * 1024) = r.u;
        }
        if (tid == 0) row_scale[b] = am * (1.f / 127.f);
    } else {
        // sign(w) -> i8, 8 elems/thread
        size_t t = ((size_t)(b - M_DIM) * blockDim.x + tid) * 8;
        float4 a = *(const float4*)(w + t);
        float4 c = *(const float4*)(w + t + 4);
        union { signed char s[8]; uint2 u; } r;
        r.s[0] = (a.x > 0.f) - (a.x < 0.f); r.s[1] = (a.y > 0.f) - (a.y < 0.f);
        r.s[2] = (a.z > 0.f) - (a.z < 0.f); r.s[3] = (a.w > 0.f) - (a.w < 0.f);
        r.s[4] = (c.x > 0.f) - (c.x < 0.f); r.s[5] = (c.y > 0.f) - (c.y < 0.f);
        r.s[6] = (c.z > 0.f) - (c.z < 0.f); r.s[7] = (c.w > 0.f) - (c.w < 0.f);
        *(uint2*)(wb + t) = r.u;
    }
}

__device__ __forceinline__ void gld_lds16(const void* g, void* l) {
    __builtin_amdgcn_global_load_lds(
        (const __attribute__((address_space(1))) void*)g,
        (__attribute__((address_space(3))) void*)l,
        16, 0, 0);
}

// ---------------------------------------------------------------------------
// i8 GEMM: 256x256 tile, BK=64, 512 thr = 8 waves (2M x 4N), wave C = 128x64
// via mfma_i32_32x32x32_i8 (acc[4][2] x intx16).
//
// Round-3 schedule = faithful m201 8-phase discipline, 2 phases per K-tile:
//   phase: { issue 6 ds_read_b128 + 2 global_load_lds;
//            s_barrier; s_waitcnt lgkmcnt(0); sched_barrier;
//            setprio(1); 8x MFMA; setprio(0); s_barrier }
//   counted vmcnt(8) ONCE per K-tile at the boundary (never 0 mid-loop);
//   lgkm is fully drained each phase AFTER the barrier (reads retire during
//   barrier-arrival skew of the 8 waves) -- this is what m201/m218 proved;
//   only the global staging pipeline stays counted across phases.
//
// LDS ring: 4 slots (128 KiB), prefetch distance 3. Writes at tile t hit slot
// (t-1)&3; all reads of that slot were lgkm-drained before the tile-t entry
// barrier by every wave -> safe.
//
// Bank-conflict-free swizzle (round-2 fix: include row bit 4):
//   f(row) = ((row>>1)&3) ^ (((row>>4)&1)<<1);  LDS[row][c] = glob[row][c^f]
//   write side: f = ((lane>>3)&3) ^ ((wave&1)<<1)   (wave-uniform bit4)
//   read  side: f = ((r5>>1)&3)  ^ (((r5>>4)&1)<<1)
//   -> any positional lane group {l,l+16,l+32,l+48} and any 8 consecutive
//      lanes hit 8 distinct bank-groups (round-2's 1.27e7 conflicts: lanes
//      16 apart shared a group because bit4 was missing from the XOR).
// ---------------------------------------------------------------------------
__global__ void __launch_bounds__(512, 2)
gemm_i8_kernel(const signed char* __restrict__ A,
               const signed char* __restrict__ B,
               const float* __restrict__ bias,
               const float* __restrict__ scale,
               const float* __restrict__ row_scale,
               float* __restrict__ out) {
    __shared__ __attribute__((aligned(16))) signed char sA[4][256 * 64];
    __shared__ __attribute__((aligned(16))) signed char sB[4][256 * 64];

    const int tid  = threadIdx.x;
    const int lane = tid & 63;
    const int wave = tid >> 6;   // 0..7
    const int wm = wave >> 2;    // 0..1 : 128-row half
    const int wn = wave & 3;     // 0..3 : 64-col slice
    const int r5 = lane & 31;
    const int hi = lane >> 5;

    // XCD-bijective swizzle: 512 blocks = 8 XCDs x 64; n-fast within XCD
    const int bid = blockIdx.x;
    const int swz = (bid & 7) * 64 + (bid >> 3);
    const int rowBase = (swz >> 4) * 256;
    const int colBase = (swz & 15) * 256;

    // ---- staging: linear LDS dest, pre-swizzled global chunk ----
    const int sc   = (lane & 3) ^ ((lane >> 3) & 3) ^ ((wave & 1) << 1);
    const int srow = wave * 16 + (lane >> 2);
    const signed char* gA0 = A + (size_t)(rowBase + srow) * K_DIM + sc * 16;
    const signed char* gA1 = gA0 + (size_t)128 * K_DIM;
    const signed char* gB0 = B + (size_t)(colBase + srow) * K_DIM + sc * 16;
    const signed char* gB1 = gB0 + (size_t)128 * K_DIM;
    const int ldsR0 = wave * 1024;
    const int ldsR1 = 8192 + wave * 1024;

    // ---- fragment read offsets (32x32x32: row=lane&31, chunk=hi+2*kstep) ----
    const int fsw = ((r5 >> 1) & 3) ^ (((r5 >> 4) & 1) << 1);
    const int ckE = ((hi + 0) ^ fsw) * 16;    // k-step 0: logical chunks {0,1}
    const int ckO = ((hi + 2) ^ fsw) * 16;    // k-step 1: logical chunks {2,3}
    const int aOff = (wm * 128 + r5) * 64;    // + mt*2048
    const int bOff = (wn * 64 + r5) * 64;     // + nt*2048

    intx16 acc[4][2] = {};

    // ---- prologue: stage tiles 0,1,2 (12 glds/wave) ----
#pragma unroll
    for (int s = 0; s < 3; ++s) {
        const size_t kg = (size_t)s * 64;
        gld_lds16(gA0 + kg, &sA[s][ldsR0]);
        gld_lds16(gA1 + kg, &sA[s][ldsR1]);
        gld_lds16(gB0 + kg, &sB[s][ldsR0]);
        gld_lds16(gB1 + kg, &sB[s][ldsR1]);
    }
    asm volatile("s_waitcnt vmcnt(8)" ::: "memory");  // tile 0 landed
    __builtin_amdgcn_s_barrier();

    for (int t = 0; t < 64; ++t) {
        const signed char* sAb = sA[t & 3];
        const signed char* sBb = sB[t & 3];
        signed char* pA = sA[(t + 3) & 3];   // slot of tile t-1: reads drained
        signed char* pB = sB[(t + 3) & 3];
        const size_t kg = (size_t)(t + 3) * 64;
        const bool stage = t < 61;

        // ================= phase A: k-step 0 =================
        intx4 fa[4], fb[2];
#pragma unroll
        for (int mt = 0; mt < 4; ++mt)
            fa[mt] = *(const intx4*)(sAb + aOff + mt * 2048 + ckE);
#pragma unroll
        for (int nt = 0; nt < 2; ++nt)
            fb[nt] = *(const intx4*)(sBb + bOff + nt * 2048 + ckE);
        if (stage) {
            gld_lds16(gA0 + kg, pA + ldsR0);
            gld_lds16(gA1 + kg, pA + ldsR1);
        }
        __builtin_amdgcn_sched_barrier(0);
        __builtin_amdgcn_s_barrier();
        asm volatile("s_waitcnt lgkmcnt(0)" ::: "memory");
        __builtin_amdgcn_sched_barrier(0);
        __builtin_amdgcn_s_setprio(1);
#pragma unroll
        for (int mt = 0; mt < 4; ++mt)
#pragma unroll
            for (int nt = 0; nt < 2; ++nt)
                acc[mt][nt] = __builtin_amdgcn_mfma_i32_32x32x32_i8(
                    fa[mt], fb[nt], acc[mt][nt], 0, 0, 0);
        __builtin_amdgcn_s_setprio(0);
        __builtin_amdgcn_sched_barrier(0);
        __builtin_amdgcn_s_barrier();

        // ================= phase B: k-step 1 =================
        intx4 oa[4], ob[2];
#pragma unroll
        for (int mt = 0; mt < 4; ++mt)
            oa[mt] = *(const intx4*)(sAb + aOff + mt * 2048 + ckO);
#pragma unroll
        for (int nt = 0; nt < 2; ++nt)
            ob[nt] = *(const intx4*)(sBb + bOff + nt * 2048 + ckO);
        if (stage) {
            gld_lds16(gB0 + kg, pB + ldsR0);
            gld_lds16(gB1 + kg, pB + ldsR1);
        }
        __builtin_amdgcn_sched_barrier(0);
        __builtin_amdgcn_s_barrier();
        asm volatile("s_waitcnt lgkmcnt(0)" ::: "memory");
        __builtin_amdgcn_sched_barrier(0);
        __builtin_amdgcn_s_setprio(1);
#pragma unroll
        for (int mt = 0; mt < 4; ++mt)
#pragma unroll
            for (int nt = 0; nt < 2; ++nt)
                acc[mt][nt] = __builtin_amdgcn_mfma_i32_32x32x32_i8(
                    oa[mt], ob[nt], acc[mt][nt], 0, 0, 0);
        __builtin_amdgcn_s_setprio(0);
        __builtin_amdgcn_sched_barrier(0);

        // ---- K-tile boundary: counted vmcnt (t+1 resident), ONE drain point
        if (t < 61)       asm volatile("s_waitcnt vmcnt(8)" ::: "memory");
        else if (t == 61) asm volatile("s_waitcnt vmcnt(4)" ::: "memory");
        else if (t == 62) asm volatile("s_waitcnt vmcnt(0)" ::: "memory");
        __builtin_amdgcn_s_barrier();
    }

    // ---- epilogue: 32x32 C/D layout col=lane&31, row=(reg&3)+8*(reg>>2)+4*hi
    const float s = scale[0];
#pragma unroll
    for (int nt = 0; nt < 2; ++nt) {
        const int gcol = colBase + wn * 64 + nt * 32 + r5;
        const float bv = bias[gcol];
#pragma unroll
        for (int mt = 0; mt < 4; ++mt) {
#pragma unroll
            for (int q = 0; q < 4; ++q) {
                const int row0 = rowBase + wm * 128 + mt * 32 + q * 8 + hi * 4;
                const float4 rs4 = *(const float4*)(row_scale + row0);
                const float rs[4] = {rs4.x, rs4.y, rs4.z, rs4.w};
#pragma unroll
                for (int r = 0; r < 4; ++r)
                    __builtin_nontemporal_store(
                        s * ((float)acc[mt][nt][q * 4 + r] * rs[r] + bv),
                        out + (size_t)(row0 + r) * N_DIM + gcol);
            }
        }
    }
}

// slow but correct fp32 fallback (only if workspace is too small)
__global__ void fallback_kernel(const float* __restrict__ x,
                                const float* __restrict__ w,
                                const float* __restrict__ bias,
                                const float* __restrict__ scale,
                                float* __restrict__ out) {
    int col = blockIdx.x * 64 + (threadIdx.x & 63);
    int row = blockIdx.y * 4 + (threadIdx.x >> 6);
    const float* xr = x + (size_t)row * K_DIM;
    const float* wr = w + (size_t)col * K_DIM;
    float acc = 0.f;
    for (int k = 0; k < K_DIM; k += 4) {
        float4 a = *(const float4*)(xr + k);
        float4 b = *(const float4*)(wr + k);
        acc += a.x * (b.x > 0.f ? 1.f : (b.x < 0.f ? -1.f : 0.f));
        acc += a.y * (b.y > 0.f ? 1.f : (b.y < 0.f ? -1.f : 0.f));
        acc += a.z * (b.z > 0.f ? 1.f : (b.z < 0.f ? -1.f : 0.f));
        acc += a.w * (b.w > 0.f ? 1.f : (b.w < 0.f ? -1.f : 0.f));
    }
    out[(size_t)row * N_DIM + col] = scale[0] * (acc + bias[col]);
}

extern "C" void kernel_launch(void* const* d_in, const int* in_sizes, int n_in,
                              void* d_out, int out_size, void* d_ws, size_t ws_size,
                              hipStream_t stream) {
    const float* x     = (const float*)d_in[0];
    const float* w     = (const float*)d_in[1];
    const float* bias  = (const float*)d_in[2];
    const float* scale = (const float*)d_in[3];
    float* out = (float*)d_out;

    const size_t xb_bytes = (size_t)M_DIM * K_DIM;          // 32 MiB
    const size_t wb_bytes = (size_t)N_DIM * K_DIM;          // 16 MiB
    const size_t need = xb_bytes + wb_bytes + M_DIM * sizeof(float);

    if (ws_size >= need) {
        signed char* xb = (signed char*)d_ws;
        signed char* wb = xb + xb_bytes;
        float* row_scale = (float*)(wb + wb_bytes);
        const unsigned w_blocks = (unsigned)((size_t)N_DIM * K_DIM / 8 / 256); // 8192
        cvt_fused_i8_kernel<<<dim3(M_DIM + w_blocks), 256, 0, stream>>>(
            x, w, xb, wb, row_scale);
        gemm_i8_kernel<<<dim3((M_DIM / 256) * (N_DIM / 256)), 512, 0, stream>>>(
            xb, wb, bias, scale, row_scale, out);
    } else {
        dim3 grid(N_DIM / 64, M_DIM / 4);
        fallback_kernel<<<grid, 256, 0, stream>>>(x, w, bias, scale, out);
    }
}